// Round 8
// baseline (803.361 us; speedup 1.0000x reference)
//
#include <hip/hip_runtime.h>
#include <hip/hip_bf16.h>

static constexpr int Bn = 8, Dn = 512, Hn = 64, Wn = 64, Kn = 1024;
static constexpr int HW = Hn * Wn;            // 4096
static constexpr int NPIX = Bn * HW;          // 32768
static constexpr size_t OFF_LOSS = (size_t)Bn * Dn * HW;          // 16777216
static constexpr size_t OFF_PROB = OFF_LOSS + 1;                   // 16777217
static constexpr size_t OFF_IDX  = OFF_PROB + (size_t)NPIX * Kn;   // 50331649
static constexpr size_t OFF_PPRB = OFF_IDX + NPIX;                 // 50364417

typedef __attribute__((ext_vector_type(8))) short short8v;
typedef __attribute__((ext_vector_type(4))) float f32x4;
typedef unsigned long long ull;

// workspace layout (bytes)
static constexpr size_t WS_CB2    = 0;        // 1024 f32
static constexpr size_t WS_XXZ    = 4096;     // 32768 f32
static constexpr size_t WS_WIDX   = 135168;   // 32768 i32
static constexpr size_t WS_NFLAG  = 266240;   // 1 i32
static constexpr size_t WS_FLAGS  = 267264;   // 32768 i32 (packed p<<10|k)
static constexpr size_t WS_REFMIN = 398336;   // 32768 u64
static constexpr size_t WS_PART   = 660480;   // 4096 f32
static constexpr size_t WS_CBBF   = 676864;   // 1024*512 bf16 (1 MB)

#define MARGIN 1e-3f

// ---- numpy pairwise-sum replica for n=512 f32 row of squares ----
__device__ float np_pairwise_sq512(const float* __restrict__ base, int stride) {
  float B[4];
#pragma unroll
  for (int blk = 0; blk < 4; blk++) {
    const float* a = base + (size_t)blk * 128 * stride;
    float r[8][4];
#pragma unroll
    for (int k = 0; k < 8; k++)
#pragma unroll
      for (int j = 0; j < 4; j++) {
        float x = a[(size_t)(4 * k + j) * stride];
        r[k][j] = __fmul_rn(x, x);
      }
#pragma unroll
    for (int i = 32; i < 128; i += 32)
#pragma unroll
      for (int k = 0; k < 8; k++)
#pragma unroll
        for (int j = 0; j < 4; j++) {
          float x = a[(size_t)(i + 4 * k + j) * stride];
          r[k][j] = __fadd_rn(r[k][j], __fmul_rn(x, x));
        }
    float L[4];
#pragma unroll
    for (int j = 0; j < 4; j++) {
      float t01 = __fadd_rn(r[0][j], r[1][j]);
      float t23 = __fadd_rn(r[2][j], r[3][j]);
      float t45 = __fadd_rn(r[4][j], r[5][j]);
      float t67 = __fadd_rn(r[6][j], r[7][j]);
      L[j] = __fadd_rn(__fadd_rn(t01, t23), __fadd_rn(t45, t67));
    }
    B[blk] = __fadd_rn(__fadd_rn(L[0], L[1]), __fadd_rn(L[2], L[3]));
  }
  return __fadd_rn(__fadd_rn(B[0], B[1]), __fadd_rn(B[2], B[3]));
}

// ---------------- K0: cvt CB->bf16 + np-replica norms + inits ----------------
__global__ __launch_bounds__(256) void k_init(const float* __restrict__ Z,
                                              const float* __restrict__ CB,
                                              unsigned short* __restrict__ CBbf,
                                              float* __restrict__ xxZ,
                                              float* __restrict__ cb2,
                                              ull* __restrict__ refmin,
                                              int* __restrict__ nflag) {
  int gid = blockIdx.x * 256 + threadIdx.x;
  {
    float2 f = *(const float2*)(CB + (size_t)gid * 2);
    union { __hip_bfloat162 h; unsigned u; } cv;
    cv.h = __float22bfloat162_rn(f);
    ((unsigned*)CBbf)[gid] = cv.u;
  }
  if (gid < NPIX) {
    int b = gid >> 12, hw = gid & 4095;
    xxZ[gid] = np_pairwise_sq512(Z + (size_t)b * Dn * HW + hw, HW);
    refmin[gid] = ~0ull;
  } else if (gid < NPIX + Kn) {
    int k = gid - NPIX;
    cb2[k] = np_pairwise_sq512(CB + (size_t)k * Dn, 1);
  }
  if (gid == 0) *nflag = 0;
}

// ---------------- K1: fused GEMM + softmax + argmin/flag ----------------
// grid (2048, 2), block 256 (4 waves). Block: 16 pixel rows (one matrix)
// x full K=1024. Wave w owns cols [w*256, w*256+256), acc[16] f32x4 = 64 VGPR.
__global__ __launch_bounds__(256) void k_fused(const float* __restrict__ Z,
                                               const float* __restrict__ ZP,
                                               const unsigned short* __restrict__ CBbf,
                                               const float* __restrict__ cb2,
                                               float* __restrict__ out,
                                               int* __restrict__ widx,
                                               int* __restrict__ nflag,
                                               int* __restrict__ flags) {
  __shared__ __align__(16) unsigned short Abf[16 * 512];  // 16KB, XOR-swizzled
  __shared__ float rv1[64];   // [wave][row]
  __shared__ int   ri1[64];
  __shared__ float rv2[64];
  __shared__ float rsum[64];
  __shared__ float rowinv_s[16];
  __shared__ float rowthr_s[16];
  __shared__ int   rowmul_s[16];
  __shared__ int pcnt, pbase;
  __shared__ int pbuf[256];

  const int py = blockIdx.x;
  const int zy = blockIdx.y;
  const int p0 = py * 16;
  const float* A = zy ? ZP : Z;
  float* S = out + (zy ? OFF_PPRB : OFF_PROB);
  const int tid = threadIdx.x;
  const int lane = tid & 63, w = tid >> 6;
  const int fr = lane & 15, fg = lane >> 4;
  if (tid == 0) pcnt = 0;

  // ---- stage A (16 pixels x 512 c) -> LDS bf16, XOR swizzle ----
  {
    const int sp = tid & 15;          // pixel row
    const int sg = tid >> 4;          // 16 groups x 32 c
    const float* Ac = A + (size_t)(p0 >> 12) * (Dn * HW) + (p0 & 4095) + sp;
#pragma unroll
    for (int j = 0; j < 4; j++) {
      int cb0 = sg * 32 + j * 8;
      float v[8];
#pragma unroll
      for (int q = 0; q < 8; q++) v[q] = Ac[(size_t)(cb0 + q) * HW];
      uint4 ua;
      union { __hip_bfloat162 h; unsigned u; } t0, t1, t2, t3;
      t0.h = __float22bfloat162_rn(make_float2(v[0], v[1]));
      t1.h = __float22bfloat162_rn(make_float2(v[2], v[3]));
      t2.h = __float22bfloat162_rn(make_float2(v[4], v[5]));
      t3.h = __float22bfloat162_rn(make_float2(v[6], v[7]));
      ua.x = t0.u; ua.y = t1.u; ua.z = t2.u; ua.w = t3.u;
      int bo = ((sp * 512 + cb0) * 2) ^ ((sp & 7) << 4);
      *(uint4*)((char*)Abf + bo) = ua;
    }
  }
  __syncthreads();

  // ---- GEMM: 16 rows x wave k-slice 256 (2 halves of 8 n) ----
  const int kbase = w * 256;
  f32x4 acc[16] = {};
#pragma unroll
  for (int c0 = 0; c0 < 512; c0 += 32) {
    int bo = ((fr * 512 + c0 + fg * 8) * 2) ^ ((fr & 7) << 4);
    short8v af = *(const short8v*)((const char*)Abf + bo);
#pragma unroll
    for (int h = 0; h < 2; h++) {
      short8v bfv[8];
#pragma unroll
      for (int n = 0; n < 8; n++)
        bfv[n] = *(const short8v*)(CBbf + (size_t)(kbase + (h * 8 + n) * 16 + fr) * 512 + c0 + fg * 8);
#pragma unroll
      for (int n = 0; n < 8; n++)
        acc[h * 8 + n] = __builtin_amdgcn_mfma_f32_16x16x32_bf16(af, bfv[n], acc[h * 8 + n], 0, 0, 0);
    }
  }

  // ---- s = cb2[k] - 2*m (xx cancels in softmax/argmin; exact path in refine)
#pragma unroll
  for (int n = 0; n < 16; n++) {
    float c2 = cb2[kbase + n * 16 + fr];
#pragma unroll
    for (int r = 0; r < 4; r++)
      acc[n][r] = __fsub_rn(c2, __fmul_rn(2.0f, acc[n][r]));
  }

  // ---- phase 1: single reduction round: (v1, i1, v2, sum) per row ----
#pragma unroll
  for (int r = 0; r < 4; r++) {
    float v1 = 1e30f, v2 = 1e30f, sum = 0.f;
    int i1 = 0x7fffffff;
#pragma unroll
    for (int n = 0; n < 16; n++) {
      float x = acc[n][r];
      int k = kbase + n * 16 + fr;
      sum += __expf(-x);
      if (x < v1) { v2 = v1; v1 = x; i1 = k; }
      else if (x < v2) { v2 = x; }
    }
#pragma unroll
    for (int d = 1; d < 16; d <<= 1) {
      float ov1 = __shfl_xor(v1, d, 64);
      int oi1 = __shfl_xor(i1, d, 64);
      float ov2 = __shfl_xor(v2, d, 64);
      float os = __shfl_xor(sum, d, 64);
      sum += os;
      float lose;
      if (ov1 < v1 || (ov1 == v1 && oi1 < i1)) { lose = v1; v1 = ov1; i1 = oi1; }
      else { lose = ov1; }
      v2 = fminf(fminf(v2, ov2), lose);
    }
    if (fr == 0) {
      int idx = w * 16 + fg * 4 + r;
      rv1[idx] = v1; ri1[idx] = i1; rv2[idx] = v2; rsum[idx] = sum;
    }
  }
  __syncthreads();

  // ---- combine 4 waves; finalize row stats; write widx for clean rows ----
  if (tid < 16) {
    float v1 = rv1[tid]; int i1 = ri1[tid]; float v2 = rv2[tid]; float sm = rsum[tid];
    for (int ww = 1; ww < 4; ww++) {
      int idx = ww * 16 + tid;
      float ov1 = rv1[idx]; int oi1 = ri1[idx]; float ov2 = rv2[idx];
      sm += rsum[idx];
      float lose;
      if (ov1 < v1 || (ov1 == v1 && oi1 < i1)) { lose = v1; v1 = ov1; i1 = oi1; }
      else { lose = ov1; }
      v2 = fminf(fminf(v2, ov2), lose);
    }
    rowinv_s[tid] = 1.0f / sm;
    rowthr_s[tid] = v1 + MARGIN;
    int multi = (v2 <= v1 + MARGIN) ? 1 : 0;
    rowmul_s[tid] = multi;
    if (zy == 0 && !multi) {   // clean row: argmin settled
      widx[p0 + tid] = i1;
      out[OFF_IDX + p0 + tid] = (float)i1;
    }
  }
  __syncthreads();

  // ---- phase 2: probs (offset-free softmax) + candidate flags ----
#pragma unroll
  for (int r = 0; r < 4; r++) {
    const int rr = fg * 4 + r;
    const float inv = rowinv_s[rr];
    const float thr = rowthr_s[rr];
    const bool multi = rowmul_s[rr] != 0;
    float* Sp = S + (size_t)(p0 + rr) * Kn + kbase + fr;
#pragma unroll
    for (int n = 0; n < 16; n++) {
      float s = acc[n][r];
      Sp[n * 16] = __expf(-s) * inv;
      if (zy == 0 && multi && s <= thr) {
        int slot = atomicAdd(&pcnt, 1);
        if (slot < 256) pbuf[slot] = ((p0 + rr) << 10) | (kbase + n * 16 + fr);
      }
    }
  }
  if (zy == 0) {
    __syncthreads();
    if (tid == 0) pbase = atomicAdd(nflag, min(pcnt, 256));
    __syncthreads();
    int npairs = min(pcnt, 256);
    if (tid < npairs) flags[pbase + tid] = pbuf[tid];
  }
}

// ---------------- K2: exact seq-fma recompute per flagged (p,k) pair ----------------
__global__ __launch_bounds__(256) void k_refine(const float* __restrict__ Z,
                                                const float* __restrict__ CB,
                                                const float* __restrict__ cb2,
                                                const float* __restrict__ xxZ,
                                                const int* __restrict__ flags,
                                                const int* __restrict__ nflag,
                                                ull* __restrict__ refmin) {
  const int np = min(*nflag, NPIX);
  for (int i = blockIdx.x * 256 + threadIdx.x; i < np; i += 256 * 256) {
    int pk = flags[i];
    int p = pk >> 10, k = pk & 1023;
    const float* zr = Z + (size_t)(p >> 12) * (Dn * HW) + (p & 4095);
    const float* cr = CB + (size_t)k * Dn;
    float m = 0.f;
    for (int c = 0; c < Dn; c++)
      m = fmaf(zr[(size_t)c * HW], cr[c], m);   // sequential, np-matching
    float d = __fsub_rn(__fadd_rn(xxZ[p], cb2[k]), __fmul_rn(2.0f, m));
    ull key = ((ull)__float_as_uint(d) << 32) | (unsigned)k;  // d>0; ties -> lowest k
    atomicMin(refmin + p, key);
  }
}

// ---------------- K3: write back refined argmin ----------------
__global__ __launch_bounds__(256) void k_refidx(const int* __restrict__ flags,
                                                const int* __restrict__ nflag,
                                                const ull* __restrict__ refmin,
                                                int* __restrict__ widx,
                                                float* __restrict__ out) {
  const int np = min(*nflag, NPIX);
  for (int i = blockIdx.x * 256 + threadIdx.x; i < np; i += 64 * 256) {
    int p = flags[i] >> 10;
    int k = (int)(refmin[p] & 0x3ffu);
    widx[p] = k;
    out[OFF_IDX + p] = (float)k;
  }
}

// ---------------- K4: z_q gather + squared-error partials ----------------
__global__ __launch_bounds__(256) void k_zqloss(const float* __restrict__ Z,
                                                const float* __restrict__ CB,
                                                const int* __restrict__ widx,
                                                float* __restrict__ out,
                                                float* __restrict__ partial) {
  __shared__ float red[256];
  const int t = threadIdx.x;
  float ls = 0.f;
  const size_t base = (size_t)blockIdx.x * 4096;
#pragma unroll
  for (int i = 0; i < 16; i++) {
    size_t e = base + (size_t)i * 256 + t;
    int hw = (int)(e & 4095);
    int c = (int)((e >> 12) & 511);
    int bb = (int)(e >> 21);
    int p = (bb << 12) | hw;
    float zv = Z[e];
    float qv = CB[(size_t)widx[p] * Dn + c];
    out[e] = qv;
    float d = zv - qv;
    ls = fmaf(d, d, ls);
  }
  red[t] = ls;
  __syncthreads();
  for (int s = 128; s > 0; s >>= 1) {
    if (t < s) red[t] += red[t + s];
    __syncthreads();
  }
  if (t == 0) partial[blockIdx.x] = red[0];
}

// ---------------- K5: finalize q_loss ----------------
__global__ __launch_bounds__(256) void k_loss(const float* __restrict__ partial,
                                              float* __restrict__ out) {
  __shared__ float red[256];
  const int t = threadIdx.x;
  float s = 0.f;
  for (int i = t; i < 4096; i += 256) s += partial[i];
  red[t] = s;
  __syncthreads();
  for (int k = 128; k > 0; k >>= 1) {
    if (t < k) red[t] += red[t + k];
    __syncthreads();
  }
  if (t == 0) out[OFF_LOSS] = red[0] * (1.25f / 16777216.0f);
}

extern "C" void kernel_launch(void* const* d_in, const int* in_sizes, int n_in,
                              void* d_out, int out_size, void* d_ws, size_t ws_size,
                              hipStream_t stream) {
  const float* Z = (const float*)d_in[0];
  const float* ZP = (const float*)d_in[1];
  const float* CB = (const float*)d_in[2];
  float* out = (float*)d_out;
  char* ws = (char*)d_ws;
  float* cb2 = (float*)(ws + WS_CB2);
  float* xxZ = (float*)(ws + WS_XXZ);
  int* widx = (int*)(ws + WS_WIDX);
  int* nflag = (int*)(ws + WS_NFLAG);
  int* flags = (int*)(ws + WS_FLAGS);
  ull* refmin = (ull*)(ws + WS_REFMIN);
  float* partial = (float*)(ws + WS_PART);
  unsigned short* CBbf = (unsigned short*)(ws + WS_CBBF);

  k_init<<<dim3(1024), 256, 0, stream>>>(Z, CB, CBbf, xxZ, cb2, refmin, nflag);
  k_fused<<<dim3(2048, 2), 256, 0, stream>>>(Z, ZP, CBbf, cb2, out, widx, nflag, flags);
  k_refine<<<dim3(256), 256, 0, stream>>>(Z, CB, cb2, xxZ, flags, nflag, refmin);
  k_refidx<<<dim3(64), 256, 0, stream>>>(flags, nflag, refmin, widx, out);
  k_zqloss<<<dim3(4096), 256, 0, stream>>>(Z, CB, widx, out, partial);
  k_loss<<<dim3(1), 256, 0, stream>>>(partial, out);
}

// Round 10
// 527.647 us; speedup vs baseline: 1.5225x; 1.5225x over previous
//
#include <hip/hip_runtime.h>
#include <hip/hip_bf16.h>

static constexpr int Bn = 8, Dn = 512, Hn = 64, Wn = 64, Kn = 1024;
static constexpr int HW = Hn * Wn;            // 4096
static constexpr int NPIX = Bn * HW;          // 32768
static constexpr size_t OFF_LOSS = (size_t)Bn * Dn * HW;          // 16777216
static constexpr size_t OFF_PROB = OFF_LOSS + 1;                   // 16777217
static constexpr size_t OFF_IDX  = OFF_PROB + (size_t)NPIX * Kn;   // 50331649
static constexpr size_t OFF_PPRB = OFF_IDX + NPIX;                 // 50364417

typedef __attribute__((ext_vector_type(8))) short short8v;
typedef __attribute__((ext_vector_type(4))) float f32x4;
typedef unsigned long long ull;

// workspace layout (bytes)
static constexpr size_t WS_CB2   = 0;         // 1024 f32
static constexpr size_t WS_XXZ   = 4096;      // 32768 f32
static constexpr size_t WS_WIDX  = 135168;    // 32768 i32
static constexpr size_t WS_PART  = 266240;    // 4096 f32
static constexpr size_t WS_CBBF  = 282624;    // 1024*512 bf16 (1 MB)
static constexpr size_t WS_ABF   = 1331200;   // optional 64 MiB A-bf16 scratch
static constexpr size_t ABF_BYTES = (size_t)2 * NPIX * Dn * 2;  // 67108864

#define MARGIN 1e-3f

__device__ inline unsigned short f2bf(float x) {
  unsigned u = __float_as_uint(x);
  u += 0x7fffu + ((u >> 16) & 1u);  // RNE
  return (unsigned short)(u >> 16);
}
__device__ inline unsigned pack2(float a, float b) {
  return (unsigned)f2bf(a) | ((unsigned)f2bf(b) << 16);
}

__device__ inline void gload_lds16(const void* g, void* l) {
  __builtin_amdgcn_global_load_lds((const __attribute__((address_space(1))) void*)g,
                                   (__attribute__((address_space(3))) void*)l, 16, 0, 0);
}

// ---- numpy pairwise-sum replica for n=512 f32 row of squares ----
__device__ float np_pairwise_sq512(const float* __restrict__ base, int stride) {
  float B[4];
#pragma unroll
  for (int blk = 0; blk < 4; blk++) {
    const float* a = base + (size_t)blk * 128 * stride;
    float r[8][4];
#pragma unroll
    for (int k = 0; k < 8; k++)
#pragma unroll
      for (int j = 0; j < 4; j++) {
        float x = a[(size_t)(4 * k + j) * stride];
        r[k][j] = __fmul_rn(x, x);
      }
#pragma unroll
    for (int i = 32; i < 128; i += 32)
#pragma unroll
      for (int k = 0; k < 8; k++)
#pragma unroll
        for (int j = 0; j < 4; j++) {
          float x = a[(size_t)(i + 4 * k + j) * stride];
          r[k][j] = __fadd_rn(r[k][j], __fmul_rn(x, x));
        }
    float L[4];
#pragma unroll
    for (int j = 0; j < 4; j++) {
      float t01 = __fadd_rn(r[0][j], r[1][j]);
      float t23 = __fadd_rn(r[2][j], r[3][j]);
      float t45 = __fadd_rn(r[4][j], r[5][j]);
      float t67 = __fadd_rn(r[6][j], r[7][j]);
      L[j] = __fadd_rn(__fadd_rn(t01, t23), __fadd_rn(t45, t67));
    }
    B[blk] = __fadd_rn(__fadd_rn(L[0], L[1]), __fadd_rn(L[2], L[3]));
  }
  return __fadd_rn(__fadd_rn(B[0], B[1]), __fadd_rn(B[2], B[3]));
}

// ---------------- K0: CB->bf16, A transpose->bf16 scratch, norms ----------
// grid 1024 x 256. A reads are px-coalesced (lane = pixel), writes contiguous.
__global__ __launch_bounds__(256) void k_init(const float* __restrict__ Z,
                                              const float* __restrict__ ZP,
                                              const float* __restrict__ CB,
                                              unsigned short* __restrict__ CBbf,
                                              unsigned short* __restrict__ Abf,
                                              float* __restrict__ xxZ,
                                              float* __restrict__ cb2) {
  int gid = blockIdx.x * 256 + threadIdx.x;
  {
    float2 f = *(const float2*)(CB + (size_t)gid * 2);
    union { __hip_bfloat162 h; unsigned u; } cv;
    cv.h = __float22bfloat162_rn(f);
    ((unsigned*)CBbf)[gid] = cv.u;
  }
  if (gid < 2 * NPIX) {
    const int p = gid & (NPIX - 1);
    const bool isz = gid < NPIX;
    const float* src = (isz ? Z : ZP) + (size_t)(p >> 12) * (Dn * HW) + (p & 4095);
    unsigned short* dst = Abf + (size_t)gid * Dn;
    float Bb[4];
#pragma unroll
    for (int blk = 0; blk < 4; blk++) {
      float rr[32];
#pragma unroll
      for (int i = 0; i < 128; i += 32) {
        float v[32];
#pragma unroll
        for (int t = 0; t < 32; t++) v[t] = src[(size_t)(blk * 128 + i + t) * HW];
        uint4 ua;
        unsigned* uw = (unsigned*)&ua;
#pragma unroll
        for (int q = 0; q < 4; q++) {
#pragma unroll
          for (int e = 0; e < 4; e++) uw[e] = pack2(v[q * 8 + 2 * e], v[q * 8 + 2 * e + 1]);
          *(uint4*)&dst[blk * 128 + i + q * 8] = ua;
        }
        if (isz) {
          if (i == 0) {
#pragma unroll
            for (int t = 0; t < 32; t++) rr[t] = __fmul_rn(v[t], v[t]);
          } else {
#pragma unroll
            for (int t = 0; t < 32; t++) rr[t] = __fadd_rn(rr[t], __fmul_rn(v[t], v[t]));
          }
        }
      }
      if (isz) {
        float L[4];
#pragma unroll
        for (int j = 0; j < 4; j++) {
          float t01 = __fadd_rn(rr[0 + j], rr[4 + j]);
          float t23 = __fadd_rn(rr[8 + j], rr[12 + j]);
          float t45 = __fadd_rn(rr[16 + j], rr[20 + j]);
          float t67 = __fadd_rn(rr[24 + j], rr[28 + j]);
          L[j] = __fadd_rn(__fadd_rn(t01, t23), __fadd_rn(t45, t67));
        }
        Bb[blk] = __fadd_rn(__fadd_rn(L[0], L[1]), __fadd_rn(L[2], L[3]));
      }
    }
    if (isz)
      xxZ[p] = __fadd_rn(__fadd_rn(Bb[0], Bb[1]), __fadd_rn(Bb[2], Bb[3]));
  } else if (gid < 2 * NPIX + Kn) {
    int k = gid - 2 * NPIX;
    cb2[k] = np_pairwise_sq512(CB + (size_t)k * Dn, 1);
  }
}

// ---------------- K1: bf16 MFMA GEMM -> s (f32, in prob slots) ----------
// grid 4096 (XCD-grouped), block 256. Tile 128px x 128k, BK=32,
// double-buffered global_load_lds staging (pre-swizzled source, linear LDS).
__global__ __launch_bounds__(256) void k_gemm(const unsigned short* __restrict__ Abf,
                                              const unsigned short* __restrict__ CBbf,
                                              const float* __restrict__ cb2,
                                              float* __restrict__ out) {
  __shared__ __align__(16) unsigned short At[2][128 * 32];
  __shared__ __align__(16) unsigned short Bt[2][128 * 32];
  __shared__ float c2s[128];

  const int b = blockIdx.x;
  const int xcd = b & 7;
  const int j = b >> 3;
  const int pair = ((j & 63) << 3) | xcd;     // (py,zz) group stays on one XCD
  const int kx = j >> 6;
  const int py = pair & 255;
  const int zz = pair >> 8;
  const int p0 = py * 128;
  const int k0 = kx * 128;
  const unsigned short* Asrc = Abf + (size_t)((zz ? NPIX : 0) + p0) * Dn;
  float* S = out + (zz ? OFF_PPRB : OFF_PROB);

  const int tid = threadIdx.x;
  const int lane = tid & 63, w = tid >> 6;
  const int fr = lane & 15, fg = lane >> 4;
  const int wm = w & 1, wn = w >> 1;
  if (tid < 128) c2s[tid] = cb2[k0 + tid];

  auto stage = [&](int buf, int c0) {
#pragma unroll
    for (int h = 0; h < 2; h++) {
      const int G = tid + h * 256;
      const int row = G >> 2, g = G & 3;
      const int gsrc = g ^ ((row >> 1) & 3);
      const int ldsbase = ((tid & 192) + h * 256) * 8;  // wave-uniform
      gload_lds16(Asrc + (size_t)row * Dn + c0 + gsrc * 8, &At[buf][ldsbase]);
      gload_lds16(CBbf + (size_t)(k0 + row) * Dn + c0 + gsrc * 8, &Bt[buf][ldsbase]);
    }
  };

  stage(0, 0);
  f32x4 acc[4][4] = {};
  const int swz = (fr >> 1) & 3;
#pragma unroll
  for (int s = 0; s < 16; s++) {
    __syncthreads();
    if (s < 15) stage((s + 1) & 1, (s + 1) * 32);
    const int cur = s & 1;
    short8v af[4], bf[4];
#pragma unroll
    for (int m = 0; m < 4; m++)
      af[m] = *(const short8v*)&At[cur][(wm * 64 + m * 16 + fr) * 32 + ((fg ^ swz) * 8)];
#pragma unroll
    for (int n = 0; n < 4; n++)
      bf[n] = *(const short8v*)&Bt[cur][(wn * 64 + n * 16 + fr) * 32 + ((fg ^ swz) * 8)];
#pragma unroll
    for (int m = 0; m < 4; m++)
#pragma unroll
      for (int n = 0; n < 4; n++)
        acc[m][n] = __builtin_amdgcn_mfma_f32_16x16x32_bf16(af[m], bf[n], acc[m][n], 0, 0, 0);
  }

  // epilogue: s = cb2[k] - 2*m (xx cancels; exact path in k_row refine)
#pragma unroll
  for (int n = 0; n < 4; n++) {
    const int kk = wn * 64 + n * 16 + fr;
    const float c2 = c2s[kk];
#pragma unroll
    for (int m = 0; m < 4; m++) {
#pragma unroll
      for (int r = 0; r < 4; r++) {
        const int px = wm * 64 + m * 16 + fg * 4 + r;
        S[(size_t)(p0 + px) * Kn + k0 + kk] =
            __fsub_rn(c2, __fmul_rn(2.0f, acc[m][n][r]));
      }
    }
  }
}

// ---------------- K2: per-row pass: stats + probs + in-wave exact refine ----
// grid (2048, 2), block 256 = 4 waves; wave owns 4 rows. NO shared memory,
// NO atomics, NO barriers: every output has a static single writer per call.
__global__ __launch_bounds__(256) void k_row(const float* __restrict__ Z,
                                             const float* __restrict__ CB,
                                             const float* __restrict__ cb2,
                                             const float* __restrict__ xxZ,
                                             float* __restrict__ out,
                                             int* __restrict__ widx) {
  const int zz = blockIdx.y;
  const int p0 = blockIdx.x * 16;
  float* S = out + (zz ? OFF_PPRB : OFF_PROB);
  const int tid = threadIdx.x;
  const int lane = tid & 63, w = tid >> 6;

#pragma unroll
  for (int i = 0; i < 4; i++) {
    const int p = p0 + w * 4 + i;
    float* Sp = S + (size_t)p * Kn;
    float v[16];
#pragma unroll
    for (int jj = 0; jj < 16; jj++) v[jj] = Sp[jj * 64 + lane];

    // (v1, i1, v2, sum) in one butterfly round
    float v1 = 1e30f, v2 = 1e30f, sum = 0.f;
    int i1 = 0x7fffffff;
#pragma unroll
    for (int jj = 0; jj < 16; jj++) {
      float x = v[jj];
      int k = jj * 64 + lane;
      sum += __expf(-x);
      if (x < v1) { v2 = v1; v1 = x; i1 = k; }
      else if (x < v2) { v2 = x; }
    }
#pragma unroll
    for (int d = 1; d < 64; d <<= 1) {
      float ov1 = __shfl_xor(v1, d, 64);
      int oi1 = __shfl_xor(i1, d, 64);
      float ov2 = __shfl_xor(v2, d, 64);
      float os = __shfl_xor(sum, d, 64);
      sum += os;
      float lose;
      if (ov1 < v1 || (ov1 == v1 && oi1 < i1)) { lose = v1; v1 = ov1; i1 = oi1; }
      else { lose = ov1; }
      v2 = fminf(fminf(v2, ov2), lose);
    }
    const float inv = 1.0f / sum;
    const float thr = v1 + MARGIN;

    // probs (offset-free softmax; xx cancels exactly)
#pragma unroll
    for (int jj = 0; jj < 16; jj++) Sp[jj * 64 + lane] = __expf(-v[jj]) * inv;

    if (zz == 0) {
      int final_idx = i1;
      if (v2 <= thr) {
        // exact f32 refine over in-margin candidates, wave-parallel dot.
        // d = fl(fl(xx+cb2[k]) - 2*dot): the ~512-magnitude add quantizes d
        // to ulp(512)=6.1e-5, swamping dot-order differences (~1e-8).
        const float* zcol = Z + (size_t)(p >> 12) * (Dn * HW) + (p & 4095);
        float zc[8];
#pragma unroll
        for (int q = 0; q < 8; q++) zc[q] = zcol[(size_t)(lane + 64 * q) * HW];
        const float xx = xxZ[p];
        float bd = 1e30f;
        int bi = 0x7fffffff;
#pragma unroll
        for (int jj = 0; jj < 16; jj++) {
          ull mask = __ballot(v[jj] <= thr);
          while (mask) {
            int l = __ffsll(mask) - 1;
            mask &= mask - 1;
            int k = jj * 64 + l;          // ascending k across (jj, l)
            const float* cr = CB + (size_t)k * Dn;
            float part = 0.f;
#pragma unroll
            for (int q = 0; q < 8; q++) part = fmaf(zc[q], cr[lane + 64 * q], part);
#pragma unroll
            for (int d = 1; d < 64; d <<= 1) part += __shfl_xor(part, d, 64);
            float dd = __fsub_rn(__fadd_rn(xx, cb2[k]), __fmul_rn(2.0f, part));
            if (dd < bd) { bd = dd; bi = k; }  // strict <: first (lowest) k wins ties
          }
        }
        final_idx = bi;
      }
      if (lane == 0) {
        widx[p] = final_idx;
        out[OFF_IDX + p] = (float)final_idx;
      }
    }
  }
}

// ---------------- K3: z_q gather + squared-error partials ----------------
__global__ __launch_bounds__(256) void k_zqloss(const float* __restrict__ Z,
                                                const float* __restrict__ CB,
                                                const int* __restrict__ widx,
                                                float* __restrict__ out,
                                                float* __restrict__ partial) {
  __shared__ float red[256];
  const int t = threadIdx.x;
  float ls = 0.f;
  const size_t base = (size_t)blockIdx.x * 4096;
#pragma unroll
  for (int i = 0; i < 16; i++) {
    size_t e = base + (size_t)i * 256 + t;
    int hw = (int)(e & 4095);
    int c = (int)((e >> 12) & 511);
    int bb = (int)(e >> 21);
    int p = (bb << 12) | hw;
    float zv = Z[e];
    float qv = CB[(size_t)widx[p] * Dn + c];
    out[e] = qv;
    float d = zv - qv;
    ls = fmaf(d, d, ls);
  }
  red[t] = ls;
  __syncthreads();
  for (int s = 128; s > 0; s >>= 1) {
    if (t < s) red[t] += red[t + s];
    __syncthreads();
  }
  if (t == 0) partial[blockIdx.x] = red[0];
}

// ---------------- K4: finalize q_loss ----------------
__global__ __launch_bounds__(256) void k_loss(const float* __restrict__ partial,
                                              float* __restrict__ out) {
  __shared__ float red[256];
  const int t = threadIdx.x;
  float s = 0.f;
  for (int i = t; i < 4096; i += 256) s += partial[i];
  red[t] = s;
  __syncthreads();
  for (int k = 128; k > 0; k >>= 1) {
    if (t < k) red[t] += red[t + k];
    __syncthreads();
  }
  if (t == 0) out[OFF_LOSS] = red[0] * (1.25f / 16777216.0f);
}

extern "C" void kernel_launch(void* const* d_in, const int* in_sizes, int n_in,
                              void* d_out, int out_size, void* d_ws, size_t ws_size,
                              hipStream_t stream) {
  const float* Z = (const float*)d_in[0];
  const float* ZP = (const float*)d_in[1];
  const float* CB = (const float*)d_in[2];
  float* out = (float*)d_out;
  char* ws = (char*)d_ws;
  float* cb2 = (float*)(ws + WS_CB2);
  float* xxZ = (float*)(ws + WS_XXZ);
  int* widx = (int*)(ws + WS_WIDX);
  float* partial = (float*)(ws + WS_PART);
  unsigned short* CBbf = (unsigned short*)(ws + WS_CBBF);
  // A-bf16 scratch: prefer d_ws; fall back to the z_q out-region (fully
  // rewritten by k_zqloss at the end of every call). ws_size is constant
  // across calls, so the choice is deterministic.
  unsigned short* Abf = (ws_size >= WS_ABF + ABF_BYTES)
                            ? (unsigned short*)(ws + WS_ABF)
                            : (unsigned short*)d_out;

  k_init<<<dim3(1024), 256, 0, stream>>>(Z, ZP, CB, CBbf, Abf, xxZ, cb2);
  k_gemm<<<dim3(4096), 256, 0, stream>>>(Abf, CBbf, cb2, out);
  k_row<<<dim3(2048, 2), 256, 0, stream>>>(Z, CB, cb2, xxZ, out, widx);
  k_zqloss<<<dim3(4096), 256, 0, stream>>>(Z, CB, widx, out, partial);
  k_loss<<<dim3(1), 256, 0, stream>>>(partial, out);
}